// Round 3
// baseline (341.650 us; speedup 1.0000x reference)
//
#include <hip/hip_runtime.h>
#include <math.h>

// Problem constants
constexpr int Uc = 512;
constexpr int Pc = 1024;
constexpr int Dc = 128;
constexpr int Hc = 256;
constexpr int Ec = 98304;
constexpr int Nc = 1536;   // U + P

// ---------------- CSR construction ----------------

__global__ void k_zero_deg(int* deg) {
    int i = blockIdx.x * 256 + threadIdx.x;
    if (i < Nc) deg[i] = 0;
}

__global__ void k_hist(const int* __restrict__ dst, int* __restrict__ deg) {
    int e = blockIdx.x * 256 + threadIdx.x;
    if (e < Ec) atomicAdd(&deg[dst[e]], 1);
}

// Single block, 256 threads. Exclusive scan of per-node edge counts (6 per thread),
// also computes dis[i] = rsqrt(deg_edges + 1)  (the +1 is the self-loop).
__global__ void k_scan(const int* __restrict__ deg, int* __restrict__ offs,
                       int* __restrict__ cursor, float* __restrict__ dis) {
    __shared__ int partial[256];
    int t = threadIdx.x;
    int base = t * 6;
    int v[6];
    int s = 0;
#pragma unroll
    for (int j = 0; j < 6; j++) { v[j] = deg[base + j]; s += v[j]; }
    partial[t] = s;
    __syncthreads();
    for (int off = 1; off < 256; off <<= 1) {
        int x = partial[t];
        int y = (t >= off) ? partial[t - off] : 0;
        __syncthreads();
        partial[t] = x + y;
        __syncthreads();
    }
    int run = (t == 0) ? 0 : partial[t - 1];
#pragma unroll
    for (int j = 0; j < 6; j++) {
        offs[base + j] = run;
        cursor[base + j] = run;
        dis[base + j] = rsqrtf((float)(v[j] + 1));
        run += v[j];
    }
    if (t == 255) offs[Nc] = run;
}

__global__ void k_scatter(const int* __restrict__ src, const int* __restrict__ dst,
                          int* __restrict__ cursor, int* __restrict__ col) {
    int e = blockIdx.x * 256 + threadIdx.x;
    if (e < Ec) {
        int p = atomicAdd(&cursor[dst[e]], 1);
        col[p] = src[e];
    }
}

// ---------------- global-read GEMM core ----------------
// 64x64 tile / 256-thread block, 4x4 per thread, no LDS (operands L1/L2-resident).
// Accumulates acc[4][4] over K. xr[r]: pointers to the 4 X rows; wc: W + c0 + tp*4.
template <int K>
__device__ __forceinline__ void gemm_acc(const float* __restrict__ xr0,
                                         const float* __restrict__ xr1,
                                         const float* __restrict__ xr2,
                                         const float* __restrict__ xr3,
                                         const float* __restrict__ wc, int M,
                                         float acc[4][4]) {
#pragma unroll 2
    for (int k = 0; k < K; k += 4) {
        float4 a[4], b[4];
        a[0] = *(const float4*)(xr0 + k);
        a[1] = *(const float4*)(xr1 + k);
        a[2] = *(const float4*)(xr2 + k);
        a[3] = *(const float4*)(xr3 + k);
#pragma unroll
        for (int j = 0; j < 4; j++) b[j] = *(const float4*)(wc + (size_t)(k + j) * M);
#pragma unroll
        for (int r = 0; r < 4; r++) {
            const float* av = (const float*)&a[r];
#pragma unroll
            for (int j = 0; j < 4; j++) {
                const float* bv = (const float*)&b[j];
#pragma unroll
                for (int c = 0; c < 4; c++) acc[r][c] += av[j] * bv[c];
            }
        }
    }
}

// Plain GEMM: Y[n,M] = X[n,K] @ W[K,M] (+bias). Grid (n/64, M/64).
template <int K>
__global__ void k_gemm_g(const float* __restrict__ X, const float* __restrict__ W,
                         const float* __restrict__ bias, float* __restrict__ Y, int M) {
    int t = threadIdx.x, tu = t >> 4, tp = t & 15;
    int r0 = blockIdx.x * 64, c0 = blockIdx.y * 64;
    int row = r0 + tu * 4;
    float acc[4][4] = {};
    gemm_acc<K>(X + (size_t)row * K, X + (size_t)(row + 1) * K,
                X + (size_t)(row + 2) * K, X + (size_t)(row + 3) * K,
                W + c0 + tp * 4, M, acc);
    float b4[4] = {0.f, 0.f, 0.f, 0.f};
    if (bias) {
        float4 bb = *(const float4*)&bias[c0 + tp * 4];
        b4[0] = bb.x; b4[1] = bb.y; b4[2] = bb.z; b4[3] = bb.w;
    }
#pragma unroll
    for (int r = 0; r < 4; r++) {
        float4 o;
        float* po = (float*)&o;
#pragma unroll
        for (int c = 0; c < 4; c++) po[c] = acc[r][c] + b4[c];
        *(float4*)&Y[(size_t)(row + r) * M + c0 + tp * 4] = o;
    }
}

// Layer-0 GEMM with fused embedding gather: rows come from ue[uid[.]] / pe[pid[.]].
__global__ void k_gemm_l0(const int* __restrict__ uid, const int* __restrict__ pid,
                          const float* __restrict__ ue, const float* __restrict__ pe,
                          const float* __restrict__ W0, float* __restrict__ Y) {
    int t = threadIdx.x, tu = t >> 4, tp = t & 15;
    int r0 = blockIdx.x * 64, c0 = blockIdx.y * 64;
    const float* xr[4];
#pragma unroll
    for (int r = 0; r < 4; r++) {
        int row = r0 + tu * 4 + r;
        xr[r] = (row < Uc) ? (ue + (size_t)uid[row] * Dc)
                           : (pe + (size_t)pid[row - Uc] * Dc);
    }
    float acc[4][4] = {};
    gemm_acc<Dc>(xr[0], xr[1], xr[2], xr[3], W0 + c0 + tp * 4, Hc, acc);
#pragma unroll
    for (int r = 0; r < 4; r++) {
        int row = r0 + tu * 4 + r;
        float4 o;
        float* po = (float*)&o;
#pragma unroll
        for (int c = 0; c < 4; c++) po[c] = acc[r][c];
        *(float4*)&Y[(size_t)row * Hc + c0 + tp * 4] = o;
    }
}

// Weight prep: Wup = Wu @ Wq1[:128,:]  (z=0),  Wpp = Wp @ Wq1[128:,:]  (z=1).
// Grid (4,4,2). Both are [256,128]@[128,256].
__global__ void k_wprep(const float* __restrict__ Wu, const float* __restrict__ Wp,
                        const float* __restrict__ Wq1, float* __restrict__ Wup,
                        float* __restrict__ Wpp) {
    int t = threadIdx.x, tu = t >> 4, tp = t & 15;
    int r0 = blockIdx.x * 64, c0 = blockIdx.y * 64;
    const float* X = blockIdx.z ? Wp : Wu;
    const float* W = Wq1 + (blockIdx.z ? (size_t)Dc * Hc : 0);
    float* Y = blockIdx.z ? Wpp : Wup;
    int row = r0 + tu * 4;
    float acc[4][4] = {};
    gemm_acc<Dc>(X + (size_t)row * Dc, X + (size_t)(row + 1) * Dc,
                 X + (size_t)(row + 2) * Dc, X + (size_t)(row + 3) * Dc,
                 W + c0 + tp * 4, Hc, acc);
#pragma unroll
    for (int r = 0; r < 4; r++) {
        float4 o;
        float* po = (float*)&o;
#pragma unroll
        for (int c = 0; c < 4; c++) po[c] = acc[r][c];
        *(float4*)&Y[(size_t)(row + r) * Hc + c0 + tp * 4] = o;
    }
}

// Bias vectors: bvu[j] = bu @ Wq1[:128,j] + bq1[j];  bvp[j] = bp @ Wq1[128:,j].
__global__ void k_bias(const float* __restrict__ bu, const float* __restrict__ bp,
                       const float* __restrict__ Wq1, const float* __restrict__ bq1,
                       float* __restrict__ bvu, float* __restrict__ bvp) {
    int j = threadIdx.x;
    float s1 = bq1[j], s2 = 0.f;
#pragma unroll 8
    for (int d = 0; d < Dc; d++) {
        s1 += bu[d] * Wq1[d * Hc + j];
        s2 += bp[d] * Wq1[(Dc + d) * Hc + j];
    }
    bvu[j] = s1;
    bvp[j] = s2;
}

// Transposed-store GEMMs for the predictor operands (merged launch, grid (24,4)):
//   bx <  8: AuT[256][512]  = (xA_users  @ Wup + bvu)^T
//   bx >= 8: ApT[256][1024] = (xA_papers @ Wpp + bvp)^T
__global__ void k_gemm_t(const float* __restrict__ xA, const float* __restrict__ Wup,
                         const float* __restrict__ Wpp, const float* __restrict__ bvu,
                         const float* __restrict__ bvp, float* __restrict__ AuT,
                         float* __restrict__ ApT) {
    int t = threadIdx.x, tu = t >> 4, tp = t & 15;
    int bx = blockIdx.x, c0 = blockIdx.y * 64;
    const float* X; const float* W; const float* bias; float* YT; int ldy; int r0;
    if (bx < 8) { X = xA;                      W = Wup; bias = bvu; YT = AuT; ldy = Uc; r0 = bx * 64; }
    else        { X = xA + (size_t)Uc * Hc;    W = Wpp; bias = bvp; YT = ApT; ldy = Pc; r0 = (bx - 8) * 64; }
    int row = r0 + tu * 4;
    float acc[4][4] = {};
    gemm_acc<Hc>(X + (size_t)row * Hc, X + (size_t)(row + 1) * Hc,
                 X + (size_t)(row + 2) * Hc, X + (size_t)(row + 3) * Hc,
                 W + c0 + tp * 4, Hc, acc);
    float4 bb = *(const float4*)&bias[c0 + tp * 4];
    const float* pb4 = (const float*)&bb;
#pragma unroll
    for (int c = 0; c < 4; c++) {
        int colj = c0 + tp * 4 + c;
        float4 o;
        o.x = acc[0][c] + pb4[c];
        o.y = acc[1][c] + pb4[c];
        o.z = acc[2][c] + pb4[c];
        o.w = acc[3][c] + pb4[c];
        *(float4*)&YT[(size_t)colj * ldy + row] = o;
    }
}

// ---------------- GCN gather (SpMM by dst) + bias + relu ----------------
// One block per node, 256 threads (one per feature). Edge idx+norm staged in LDS.
__global__ void k_gcn_gather(const float* __restrict__ h, const int* __restrict__ offs,
                             const int* __restrict__ col, const float* __restrict__ dis,
                             const float* __restrict__ bias, float* __restrict__ out) {
    __shared__ int   sidx[256];
    __shared__ float snrm[256];
    int i = blockIdx.x;
    int f = threadIdx.x;
    float di = dis[i];
    float acc = h[i * Hc + f] * di * di;   // self-loop
    int e0 = offs[i], e1 = offs[i + 1];
    for (int base = e0; base < e1; base += 256) {
        int cnt = min(256, e1 - base);
        __syncthreads();
        if (f < cnt) {
            int s = col[base + f];
            sidx[f] = s * Hc;
            snrm[f] = dis[s] * di;
        }
        __syncthreads();
        int j = 0;
        for (; j + 4 <= cnt; j += 4) {
            float h0 = h[sidx[j] + f],     h1 = h[sidx[j + 1] + f];
            float h2 = h[sidx[j + 2] + f], h3 = h[sidx[j + 3] + f];
            acc += h0 * snrm[j] + h1 * snrm[j + 1] + h2 * snrm[j + 2] + h3 * snrm[j + 3];
        }
        for (; j < cnt; j++) acc += h[sidx[j] + f] * snrm[j];
    }
    out[i * Hc + f] = fmaxf(acc + bias[f], 0.f);
}

// ---------------- predictor ----------------
// pred[u,p] = sigmoid( sum_k relu(AuT[k][u] + ApT[k][p]) * Wq2[k] + bq2 )
// Grid (U/32, P/64) = (16,16) = 256 blocks; 256 threads; 4 users x 2 papers / thread.
// All operands read from global (L1/L2-resident); no LDS, no barriers.
__global__ void k_pred(const float* __restrict__ AuT, const float* __restrict__ ApT,
                       const float* __restrict__ Wq2, const float* __restrict__ bq2,
                       float* __restrict__ out) {
    int t = threadIdx.x;
    int ub = blockIdx.x * 32, pb = blockIdx.y * 64;
    int tu = t >> 5, tp = t & 31;          // tu 0..7 (4 users), tp 0..31 (2 papers)
    const float* aup = AuT + ub + tu * 4;
    const float* app = ApT + pb + tp * 2;
    float acc[4][2] = {};
#pragma unroll 2
    for (int k = 0; k < Hc; k += 4) {
        float4 wv = *(const float4*)&Wq2[k];   // wave-uniform -> s_load
        float4 a[4];
        float2 p[4];
#pragma unroll
        for (int j = 0; j < 4; j++) a[j] = *(const float4*)(aup + (size_t)(k + j) * Uc);
#pragma unroll
        for (int j = 0; j < 4; j++) p[j] = *(const float2*)(app + (size_t)(k + j) * Pc);
        const float* w = (const float*)&wv;
#pragma unroll
        for (int j = 0; j < 4; j++) {
            const float* av = (const float*)&a[j];
            float p0 = p[j].x, p1 = p[j].y;
#pragma unroll
            for (int r = 0; r < 4; r++) {
                acc[r][0] += fmaxf(av[r] + p0, 0.f) * w[j];
                acc[r][1] += fmaxf(av[r] + p1, 0.f) * w[j];
            }
        }
    }
    float bq = bq2[0];
#pragma unroll
    for (int r = 0; r < 4; r++) {
        int u = ub + tu * 4 + r;
        float2 o;
        o.x = 1.f / (1.f + __expf(-(acc[r][0] + bq)));
        o.y = 1.f / (1.f + __expf(-(acc[r][1] + bq)));
        *(float2*)&out[(size_t)u * Pc + pb + tp * 2] = o;
    }
}

// ---------------- launcher ----------------

extern "C" void kernel_launch(void* const* d_in, const int* in_sizes, int n_in,
                              void* d_out, int out_size, void* d_ws, size_t ws_size,
                              hipStream_t stream) {
    const int*   uid = (const int*)d_in[0];
    const int*   pid = (const int*)d_in[1];
    const int*   ei  = (const int*)d_in[2];   // [2,E]: src = ei[0..E), dst = ei[E..2E)
    const float* ue  = (const float*)d_in[4];
    const float* pe  = (const float*)d_in[5];
    const float* W0  = (const float*)d_in[6];  const float* b0 = (const float*)d_in[7];
    const float* W1  = (const float*)d_in[8];  const float* b1 = (const float*)d_in[9];
    const float* W2  = (const float*)d_in[10]; const float* b2 = (const float*)d_in[11];
    const float* Wu  = (const float*)d_in[12]; const float* bu = (const float*)d_in[13];
    const float* Wp  = (const float*)d_in[14]; const float* bp = (const float*)d_in[15];
    const float* Wq1 = (const float*)d_in[16]; const float* bq1 = (const float*)d_in[17];
    const float* Wq2 = (const float*)d_in[18]; const float* bq2 = (const float*)d_in[19];

    const int* e_src = ei;
    const int* e_dst = ei + Ec;

    char* w = (char*)d_ws;
    auto alloc = [&](size_t bytes) { char* p = w; w += (bytes + 255) & ~size_t(255); return p; };
    int*   deg    = (int*)alloc(Nc * 4);
    int*   offs   = (int*)alloc((Nc + 1) * 4);
    int*   cursor = (int*)alloc(Nc * 4);
    int*   col    = (int*)alloc(Ec * 4);
    float* dis    = (float*)alloc(Nc * 4);
    float* xA     = (float*)alloc((size_t)Nc * Hc * 4);
    float* Hbuf   = (float*)alloc((size_t)Nc * Hc * 4);
    float* Wup    = (float*)alloc((size_t)Hc * Hc * 4);
    float* Wpp    = (float*)alloc((size_t)Hc * Hc * 4);
    float* bvu    = (float*)alloc(Hc * 4);
    float* bvp    = (float*)alloc(Hc * 4);
    float* AuT    = (float*)alloc((size_t)Hc * Uc * 4);
    float* ApT    = (float*)alloc((size_t)Hc * Pc * 4);
    float* pred   = (float*)d_out;

    // CSR by dst
    k_zero_deg<<<(Nc + 255) / 256, 256, 0, stream>>>(deg);
    k_hist<<<Ec / 256, 256, 0, stream>>>(e_dst, deg);
    k_scan<<<1, 256, 0, stream>>>(deg, offs, cursor, dis);
    k_scatter<<<Ec / 256, 256, 0, stream>>>(e_src, e_dst, cursor, col);

    // Layer 0 (embedding gather fused into GEMM)
    k_gemm_l0<<<dim3(Nc / 64, Hc / 64), 256, 0, stream>>>(uid, pid, ue, pe, W0, Hbuf);
    k_gcn_gather<<<Nc, Hc, 0, stream>>>(Hbuf, offs, col, dis, b0, xA);
    // Layer 1
    k_gemm_g<Hc><<<dim3(Nc / 64, Hc / 64), 256, 0, stream>>>(xA, W1, nullptr, Hbuf, Hc);
    k_gcn_gather<<<Nc, Hc, 0, stream>>>(Hbuf, offs, col, dis, b1, xA);
    // Layer 2
    k_gemm_g<Hc><<<dim3(Nc / 64, Hc / 64), 256, 0, stream>>>(xA, W2, nullptr, Hbuf, Hc);
    k_gcn_gather<<<Nc, Hc, 0, stream>>>(Hbuf, offs, col, dis, b2, xA);

    // Collapsed predictor-input weights + biases
    k_wprep<<<dim3(4, 4, 2), 256, 0, stream>>>(Wu, Wp, Wq1, Wup, Wpp);
    k_bias<<<1, 256, 0, stream>>>(bu, bp, Wq1, bq1, bvu, bvp);

    // AuT / ApT (transposed store), merged launch
    k_gemm_t<<<dim3(24, 4), 256, 0, stream>>>(xA, Wup, Wpp, bvu, bvp, AuT, ApT);

    // predictor
    k_pred<<<dim3(Uc / 32, Pc / 64), 256, 0, stream>>>(AuT, ApT, Wq2, bq2, pred);
}

// Round 4
// 300.060 us; speedup vs baseline: 1.1386x; 1.1386x over previous
//
#include <hip/hip_runtime.h>
#include <math.h>

// Problem constants
constexpr int Uc = 512;
constexpr int Pc = 1024;
constexpr int Dc = 128;
constexpr int Hc = 256;
constexpr int Ec = 98304;
constexpr int Nc = 1536;   // U + P

// ---------------- CSR construction ----------------

__global__ void k_zero_deg(int* deg) {
    int i = blockIdx.x * 256 + threadIdx.x;
    if (i < Nc) deg[i] = 0;
}

__global__ void k_hist(const int* __restrict__ dst, int* __restrict__ deg) {
    int e = blockIdx.x * 256 + threadIdx.x;
    if (e < Ec) atomicAdd(&deg[dst[e]], 1);
}

// Single block, 256 threads. Exclusive scan of per-node edge counts (6 per thread),
// also computes dis[i] = rsqrt(deg_edges + 1)  (the +1 is the self-loop).
__global__ void k_scan(const int* __restrict__ deg, int* __restrict__ offs,
                       int* __restrict__ cursor, float* __restrict__ dis) {
    __shared__ int partial[256];
    int t = threadIdx.x;
    int base = t * 6;
    int v[6];
    int s = 0;
#pragma unroll
    for (int j = 0; j < 6; j++) { v[j] = deg[base + j]; s += v[j]; }
    partial[t] = s;
    __syncthreads();
    for (int off = 1; off < 256; off <<= 1) {
        int x = partial[t];
        int y = (t >= off) ? partial[t - off] : 0;
        __syncthreads();
        partial[t] = x + y;
        __syncthreads();
    }
    int run = (t == 0) ? 0 : partial[t - 1];
#pragma unroll
    for (int j = 0; j < 6; j++) {
        offs[base + j] = run;
        cursor[base + j] = run;
        dis[base + j] = rsqrtf((float)(v[j] + 1));
        run += v[j];
    }
    if (t == 255) offs[Nc] = run;
}

__global__ void k_scatter(const int* __restrict__ src, const int* __restrict__ dst,
                          int* __restrict__ cursor, int* __restrict__ col) {
    int e = blockIdx.x * 256 + threadIdx.x;
    if (e < Ec) {
        int p = atomicAdd(&cursor[dst[e]], 1);
        col[p] = src[e];
    }
}

// ---------------- global-read GEMM core: 32x32 tile, 256 thr, 2x2/thread ----------
// tx = t&15 -> cols c0+tx*2..+2 ; ty = t>>4 (0..15) -> rows r0+ty*2..+2.
// A loads broadcast across the 16 same-ty lanes; B loads 128 B coalesced per wave.
template <int K>
__device__ __forceinline__ void gemm_core(const float* __restrict__ xr0,
                                          const float* __restrict__ xr1,
                                          const float* __restrict__ wc, int M,
                                          float acc[2][2]) {
#pragma unroll 4
    for (int k = 0; k < K; k += 4) {
        float4 a0 = *(const float4*)(xr0 + k);
        float4 a1 = *(const float4*)(xr1 + k);
        float2 b[4];
#pragma unroll
        for (int j = 0; j < 4; j++) b[j] = *(const float2*)(wc + (size_t)(k + j) * M);
        const float* a0v = (const float*)&a0;
        const float* a1v = (const float*)&a1;
#pragma unroll
        for (int j = 0; j < 4; j++) {
            acc[0][0] += a0v[j] * b[j].x;
            acc[0][1] += a0v[j] * b[j].y;
            acc[1][0] += a1v[j] * b[j].x;
            acc[1][1] += a1v[j] * b[j].y;
        }
    }
}

// Plain GEMM: Y[n,M] = X[n,K] @ W[K,M]. Grid (n/32, M/32), 256 threads.
template <int K>
__global__ void k_gemm(const float* __restrict__ X, const float* __restrict__ W,
                       float* __restrict__ Y, int M) {
    int t = threadIdx.x, tx = t & 15, ty = t >> 4;
    int r0 = blockIdx.x * 32, c0 = blockIdx.y * 32;
    int row = r0 + ty * 2;
    float acc[2][2] = {};
    gemm_core<K>(X + (size_t)row * K, X + (size_t)(row + 1) * K,
                 W + c0 + tx * 2, M, acc);
    *(float2*)&Y[(size_t)row * M + c0 + tx * 2] = make_float2(acc[0][0], acc[0][1]);
    *(float2*)&Y[(size_t)(row + 1) * M + c0 + tx * 2] = make_float2(acc[1][0], acc[1][1]);
}

// Layer-0 GEMM with fused embedding gather.
__global__ void k_gemm_l0(const int* __restrict__ uid, const int* __restrict__ pid,
                          const float* __restrict__ ue, const float* __restrict__ pe,
                          const float* __restrict__ W0, float* __restrict__ Y) {
    int t = threadIdx.x, tx = t & 15, ty = t >> 4;
    int r0 = blockIdx.x * 32, c0 = blockIdx.y * 32;
    int row = r0 + ty * 2;
    const float* xr0 = (row < Uc) ? (ue + (size_t)uid[row] * Dc)
                                  : (pe + (size_t)pid[row - Uc] * Dc);
    const float* xr1 = (row + 1 < Uc) ? (ue + (size_t)uid[row + 1] * Dc)
                                      : (pe + (size_t)pid[row + 1 - Uc] * Dc);
    float acc[2][2] = {};
    gemm_core<Dc>(xr0, xr1, W0 + c0 + tx * 2, Hc, acc);
    *(float2*)&Y[(size_t)row * Hc + c0 + tx * 2] = make_float2(acc[0][0], acc[0][1]);
    *(float2*)&Y[(size_t)(row + 1) * Hc + c0 + tx * 2] = make_float2(acc[1][0], acc[1][1]);
}

// Weight prep. Grid (8,8,3):
//   z=0: Wup = Wu @ Wq1[:128,:]   z=1: Wpp = Wp @ Wq1[128:,:]
//   z=2 (bx==0 only): bvu[j] = bu@Wq1[:128,j] + bq1[j]; bvp[j] = bp@Wq1[128:,j]
__global__ void k_wprep(const float* __restrict__ Wu, const float* __restrict__ Wp,
                        const float* __restrict__ Wq1, const float* __restrict__ bu,
                        const float* __restrict__ bp, const float* __restrict__ bq1,
                        float* __restrict__ Wup, float* __restrict__ Wpp,
                        float* __restrict__ bvu, float* __restrict__ bvp) {
    int t = threadIdx.x;
    int c0 = blockIdx.y * 32;
    if (blockIdx.z == 2) {
        if (blockIdx.x != 0) return;
        if (t < 32) {
            int j = c0 + t;
            float s = bq1[j];
#pragma unroll 8
            for (int d = 0; d < Dc; d++) s += bu[d] * Wq1[d * Hc + j];
            bvu[j] = s;
        } else if (t < 64) {
            int j = c0 + t - 32;
            float s = 0.f;
#pragma unroll 8
            for (int d = 0; d < Dc; d++) s += bp[d] * Wq1[(Dc + d) * Hc + j];
            bvp[j] = s;
        }
        return;
    }
    int tx = t & 15, ty = t >> 4;
    int r0 = blockIdx.x * 32;
    const float* X = blockIdx.z ? Wp : Wu;
    const float* W = Wq1 + (blockIdx.z ? (size_t)Dc * Hc : 0);
    float* Y = blockIdx.z ? Wpp : Wup;
    int row = r0 + ty * 2;
    float acc[2][2] = {};
    gemm_core<Dc>(X + (size_t)row * Dc, X + (size_t)(row + 1) * Dc,
                  W + c0 + tx * 2, Hc, acc);
    *(float2*)&Y[(size_t)row * Hc + c0 + tx * 2] = make_float2(acc[0][0], acc[0][1]);
    *(float2*)&Y[(size_t)(row + 1) * Hc + c0 + tx * 2] = make_float2(acc[1][0], acc[1][1]);
}

// Transposed-store GEMM for predictor operands. Grid (48,8), 256 threads.
//   bx < 16:  AuT[256][512]  = (xA_users  @ Wup + bvu)^T
//   bx >= 16: ApT[256][1024] = (xA_papers @ Wpp + bvp)^T
__global__ void k_gemm_t(const float* __restrict__ xA, const float* __restrict__ Wup,
                         const float* __restrict__ Wpp, const float* __restrict__ bvu,
                         const float* __restrict__ bvp, float* __restrict__ AuT,
                         float* __restrict__ ApT) {
    int t = threadIdx.x, tx = t & 15, ty = t >> 4;
    int bx = blockIdx.x, c0 = blockIdx.y * 32;
    const float* X; const float* W; const float* bias; float* YT; int ldy; int r0;
    if (bx < 16) { X = xA;                   W = Wup; bias = bvu; YT = AuT; ldy = Uc; r0 = bx * 32; }
    else         { X = xA + (size_t)Uc * Hc; W = Wpp; bias = bvp; YT = ApT; ldy = Pc; r0 = (bx - 16) * 32; }
    int row = r0 + ty * 2;
    float acc[2][2] = {};
    gemm_core<Hc>(X + (size_t)row * Hc, X + (size_t)(row + 1) * Hc,
                  W + c0 + tx * 2, Hc, acc);
    float2 bb = *(const float2*)&bias[c0 + tx * 2];
    *(float2*)&YT[(size_t)(c0 + tx * 2) * ldy + row] =
        make_float2(acc[0][0] + bb.x, acc[1][0] + bb.x);
    *(float2*)&YT[(size_t)(c0 + tx * 2 + 1) * ldy + row] =
        make_float2(acc[0][1] + bb.y, acc[1][1] + bb.y);
}

// ---------------- GCN gather (SpMM by dst) + bias + relu ----------------
// One block per node, 256 threads (one per feature). Edge idx+norm staged in LDS.
__global__ void k_gcn_gather(const float* __restrict__ h, const int* __restrict__ offs,
                             const int* __restrict__ col, const float* __restrict__ dis,
                             const float* __restrict__ bias, float* __restrict__ out) {
    __shared__ int   sidx[256];
    __shared__ float snrm[256];
    int i = blockIdx.x;
    int f = threadIdx.x;
    float di = dis[i];
    float acc = h[i * Hc + f] * di * di;   // self-loop
    int e0 = offs[i], e1 = offs[i + 1];
    for (int base = e0; base < e1; base += 256) {
        int cnt = min(256, e1 - base);
        __syncthreads();
        if (f < cnt) {
            int s = col[base + f];
            sidx[f] = s * Hc;
            snrm[f] = dis[s] * di;
        }
        __syncthreads();
        int j = 0;
        for (; j + 4 <= cnt; j += 4) {
            float h0 = h[sidx[j] + f],     h1 = h[sidx[j + 1] + f];
            float h2 = h[sidx[j + 2] + f], h3 = h[sidx[j + 3] + f];
            acc += h0 * snrm[j] + h1 * snrm[j + 1] + h2 * snrm[j + 2] + h3 * snrm[j + 3];
        }
        for (; j < cnt; j++) acc += h[sidx[j] + f] * snrm[j];
    }
    out[i * Hc + f] = fmaxf(acc + bias[f], 0.f);
}

// ---------------- predictor ----------------
// pred[u,p] = sigmoid( sum_k relu(AuT[k][u] + ApT[k][p]) * Wq2[k] + bq2 )
// Grid (16,16) = 256 blocks; 256 threads; 4 users x 2 papers / thread. No LDS.
__global__ void k_pred(const float* __restrict__ AuT, const float* __restrict__ ApT,
                       const float* __restrict__ Wq2, const float* __restrict__ bq2,
                       float* __restrict__ out) {
    int t = threadIdx.x;
    int ub = blockIdx.x * 32, pb = blockIdx.y * 64;
    int tu = t >> 5, tp = t & 31;          // tu 0..7 (4 users), tp 0..31 (2 papers)
    const float* aup = AuT + ub + tu * 4;
    const float* app = ApT + pb + tp * 2;
    float acc[4][2] = {};
#pragma unroll 2
    for (int k = 0; k < Hc; k += 4) {
        float4 wv = *(const float4*)&Wq2[k];   // wave-uniform -> s_load
        float4 a[4];
        float2 p[4];
#pragma unroll
        for (int j = 0; j < 4; j++) a[j] = *(const float4*)(aup + (size_t)(k + j) * Uc);
#pragma unroll
        for (int j = 0; j < 4; j++) p[j] = *(const float2*)(app + (size_t)(k + j) * Pc);
        const float* w = (const float*)&wv;
#pragma unroll
        for (int j = 0; j < 4; j++) {
            const float* av = (const float*)&a[j];
            float p0 = p[j].x, p1 = p[j].y;
#pragma unroll
            for (int r = 0; r < 4; r++) {
                acc[r][0] += fmaxf(av[r] + p0, 0.f) * w[j];
                acc[r][1] += fmaxf(av[r] + p1, 0.f) * w[j];
            }
        }
    }
    float bq = bq2[0];
#pragma unroll
    for (int r = 0; r < 4; r++) {
        int u = ub + tu * 4 + r;
        float2 o;
        o.x = 1.f / (1.f + __expf(-(acc[r][0] + bq)));
        o.y = 1.f / (1.f + __expf(-(acc[r][1] + bq)));
        *(float2*)&out[(size_t)u * Pc + pb + tp * 2] = o;
    }
}

// ---------------- launcher ----------------

extern "C" void kernel_launch(void* const* d_in, const int* in_sizes, int n_in,
                              void* d_out, int out_size, void* d_ws, size_t ws_size,
                              hipStream_t stream) {
    const int*   uid = (const int*)d_in[0];
    const int*   pid = (const int*)d_in[1];
    const int*   ei  = (const int*)d_in[2];   // [2,E]: src = ei[0..E), dst = ei[E..2E)
    const float* ue  = (const float*)d_in[4];
    const float* pe  = (const float*)d_in[5];
    const float* W0  = (const float*)d_in[6];  const float* b0 = (const float*)d_in[7];
    const float* W1  = (const float*)d_in[8];  const float* b1 = (const float*)d_in[9];
    const float* W2  = (const float*)d_in[10]; const float* b2 = (const float*)d_in[11];
    const float* Wu  = (const float*)d_in[12]; const float* bu = (const float*)d_in[13];
    const float* Wp  = (const float*)d_in[14]; const float* bp = (const float*)d_in[15];
    const float* Wq1 = (const float*)d_in[16]; const float* bq1 = (const float*)d_in[17];
    const float* Wq2 = (const float*)d_in[18]; const float* bq2 = (const float*)d_in[19];

    const int* e_src = ei;
    const int* e_dst = ei + Ec;

    char* w = (char*)d_ws;
    auto alloc = [&](size_t bytes) { char* p = w; w += (bytes + 255) & ~size_t(255); return p; };
    int*   deg    = (int*)alloc(Nc * 4);
    int*   offs   = (int*)alloc((Nc + 1) * 4);
    int*   cursor = (int*)alloc(Nc * 4);
    int*   col    = (int*)alloc(Ec * 4);
    float* dis    = (float*)alloc(Nc * 4);
    float* xA     = (float*)alloc((size_t)Nc * Hc * 4);
    float* Hbuf   = (float*)alloc((size_t)Nc * Hc * 4);
    float* Wup    = (float*)alloc((size_t)Hc * Hc * 4);
    float* Wpp    = (float*)alloc((size_t)Hc * Hc * 4);
    float* bvu    = (float*)alloc(Hc * 4);
    float* bvp    = (float*)alloc(Hc * 4);
    float* AuT    = (float*)alloc((size_t)Hc * Uc * 4);
    float* ApT    = (float*)alloc((size_t)Hc * Pc * 4);
    float* pred   = (float*)d_out;

    // CSR by dst
    k_zero_deg<<<(Nc + 255) / 256, 256, 0, stream>>>(deg);
    k_hist<<<Ec / 256, 256, 0, stream>>>(e_dst, deg);
    k_scan<<<1, 256, 0, stream>>>(deg, offs, cursor, dis);
    k_scatter<<<Ec / 256, 256, 0, stream>>>(e_src, e_dst, cursor, col);

    // Collapsed predictor-input weights + biases (no upstream deps)
    k_wprep<<<dim3(8, 8, 3), 256, 0, stream>>>(Wu, Wp, Wq1, bu, bp, bq1, Wup, Wpp, bvu, bvp);

    // Layer 0 (embedding gather fused into GEMM)
    k_gemm_l0<<<dim3(Nc / 32, Hc / 32), 256, 0, stream>>>(uid, pid, ue, pe, W0, Hbuf);
    k_gcn_gather<<<Nc, Hc, 0, stream>>>(Hbuf, offs, col, dis, b0, xA);
    // Layer 1
    k_gemm<Hc><<<dim3(Nc / 32, Hc / 32), 256, 0, stream>>>(xA, W1, Hbuf, Hc);
    k_gcn_gather<<<Nc, Hc, 0, stream>>>(Hbuf, offs, col, dis, b1, xA);
    // Layer 2
    k_gemm<Hc><<<dim3(Nc / 32, Hc / 32), 256, 0, stream>>>(xA, W2, Hbuf, Hc);
    k_gcn_gather<<<Nc, Hc, 0, stream>>>(Hbuf, offs, col, dis, b2, xA);

    // AuT / ApT (transposed store), merged launch
    k_gemm_t<<<dim3(48, 8), 256, 0, stream>>>(xA, Wup, Wpp, bvu, bvp, AuT, ApT);

    // predictor
    k_pred<<<dim3(Uc / 32, Pc / 64), 256, 0, stream>>>(AuT, ApT, Wq2, bq2, pred);
}

// Round 5
// 299.294 us; speedup vs baseline: 1.1415x; 1.0026x over previous
//
#include <hip/hip_runtime.h>
#include <math.h>

// Problem constants
constexpr int Uc = 512;
constexpr int Pc = 1024;
constexpr int Dc = 128;
constexpr int Hc = 256;
constexpr int Ec = 98304;
constexpr int Nc = 1536;   // U + P

// ---------------- CSR construction ----------------

__global__ void k_hist(const int* __restrict__ dst, int* __restrict__ deg) {
    int e = blockIdx.x * 256 + threadIdx.x;
    if (e < Ec) atomicAdd(&deg[dst[e]], 1);
}

// Single block, 256 threads. Exclusive scan of per-node edge counts (6 per thread),
// also computes dis[i] = rsqrt(deg_edges + 1)  (the +1 is the self-loop).
__global__ void k_scan(const int* __restrict__ deg, int* __restrict__ offs,
                       int* __restrict__ cursor, float* __restrict__ dis) {
    __shared__ int partial[256];
    int t = threadIdx.x;
    int base = t * 6;
    int v[6];
    int s = 0;
#pragma unroll
    for (int j = 0; j < 6; j++) { v[j] = deg[base + j]; s += v[j]; }
    partial[t] = s;
    __syncthreads();
    for (int off = 1; off < 256; off <<= 1) {
        int x = partial[t];
        int y = (t >= off) ? partial[t - off] : 0;
        __syncthreads();
        partial[t] = x + y;
        __syncthreads();
    }
    int run = (t == 0) ? 0 : partial[t - 1];
#pragma unroll
    for (int j = 0; j < 6; j++) {
        offs[base + j] = run;
        cursor[base + j] = run;
        dis[base + j] = rsqrtf((float)(v[j] + 1));
        run += v[j];
    }
    if (t == 255) offs[Nc] = run;
}

__global__ void k_scatter(const int* __restrict__ src, const int* __restrict__ dst,
                          int* __restrict__ cursor, int* __restrict__ col) {
    int e = blockIdx.x * 256 + threadIdx.x;
    if (e < Ec) {
        int p = atomicAdd(&cursor[dst[e]], 1);
        col[p] = src[e];
    }
}

// ---------------- GEMM core: 16 rows x 32 cols / 256-thread block ----------------
// tx = t&15 -> 2 cols; ty = t>>4 -> 1 row. A loads broadcast over 16 lanes,
// B float2 loads coalesce into 2 lines/wave. 2 independent acc chains/thread.
template <int K>
__device__ __forceinline__ void gemm_core16(const float* __restrict__ xr,
                                            const float* __restrict__ wc, int M,
                                            float& acc0, float& acc1) {
#pragma unroll 4
    for (int k = 0; k < K; k += 4) {
        float4 a = *(const float4*)(xr + k);
        float2 b0 = *(const float2*)(wc + (size_t)k * M);
        float2 b1 = *(const float2*)(wc + (size_t)(k + 1) * M);
        float2 b2 = *(const float2*)(wc + (size_t)(k + 2) * M);
        float2 b3 = *(const float2*)(wc + (size_t)(k + 3) * M);
        acc0 += a.x * b0.x; acc1 += a.x * b0.y;
        acc0 += a.y * b1.x; acc1 += a.y * b1.y;
        acc0 += a.z * b2.x; acc1 += a.z * b2.y;
        acc0 += a.w * b3.x; acc1 += a.w * b3.y;
    }
}

// GCN-layer GEMM with dis-scaled epilogue: Y[row,:] = ds[row] * (X @ W)[row,:].
// Grid (n/16, M/32), 256 threads.
template <int K>
__global__ void k_gemm_s(const float* __restrict__ X, const float* __restrict__ W,
                         const float* __restrict__ ds, float* __restrict__ Y, int M) {
    int t = threadIdx.x, tx = t & 15, ty = t >> 4;
    int row = blockIdx.x * 16 + ty;
    int col = blockIdx.y * 32 + tx * 2;
    float a0 = 0.f, a1 = 0.f;
    gemm_core16<K>(X + (size_t)row * K, W + col, M, a0, a1);
    float s = ds[row];
    *(float2*)&Y[(size_t)row * M + col] = make_float2(a0 * s, a1 * s);
}

// Layer-0: rows gathered from embeddings, dis-scaled epilogue.
__global__ void k_gemm_l0(const int* __restrict__ uid, const int* __restrict__ pid,
                          const float* __restrict__ ue, const float* __restrict__ pe,
                          const float* __restrict__ W0, const float* __restrict__ ds,
                          float* __restrict__ Y) {
    int t = threadIdx.x, tx = t & 15, ty = t >> 4;
    int row = blockIdx.x * 16 + ty;
    int col = blockIdx.y * 32 + tx * 2;
    const float* xr = (row < Uc) ? (ue + (size_t)uid[row] * Dc)
                                 : (pe + (size_t)pid[row - Uc] * Dc);
    float a0 = 0.f, a1 = 0.f;
    gemm_core16<Dc>(xr, W0 + col, Hc, a0, a1);
    float s = ds[row];
    *(float2*)&Y[(size_t)row * Hc + col] = make_float2(a0 * s, a1 * s);
}

// Weight prep. Grid (16,8,3):
//   z=0: Wup = Wu @ Wq1[:128,:]   z=1: Wpp = Wp @ Wq1[128:,:]
//   z=2: bx==0 -> bvu[j] = bu@Wq1[:128,j] + bq1[j]; bx==1 -> bvp[j] = bp@Wq1[128:,j]
__global__ void k_wprep(const float* __restrict__ Wu, const float* __restrict__ Wp,
                        const float* __restrict__ Wq1, const float* __restrict__ bu,
                        const float* __restrict__ bp, const float* __restrict__ bq1,
                        float* __restrict__ Wup, float* __restrict__ Wpp,
                        float* __restrict__ bvu, float* __restrict__ bvp) {
    int t = threadIdx.x;
    if (blockIdx.z == 2) {
        if (blockIdx.y != 0) return;
        if (blockIdx.x == 0) {
            float s = bq1[t];
#pragma unroll 8
            for (int d = 0; d < Dc; d++) s += bu[d] * Wq1[d * Hc + t];
            bvu[t] = s;
        } else if (blockIdx.x == 1) {
            float s = 0.f;
#pragma unroll 8
            for (int d = 0; d < Dc; d++) s += bp[d] * Wq1[(Dc + d) * Hc + t];
            bvp[t] = s;
        }
        return;
    }
    int tx = t & 15, ty = t >> 4;
    int row = blockIdx.x * 16 + ty;
    int col = blockIdx.y * 32 + tx * 2;
    const float* X = blockIdx.z ? Wp : Wu;
    const float* W = Wq1 + (blockIdx.z ? (size_t)Dc * Hc : 0);
    float* Y = blockIdx.z ? Wpp : Wup;
    float a0 = 0.f, a1 = 0.f;
    gemm_core16<Dc>(X + (size_t)row * Dc, W + col, Hc, a0, a1);
    *(float2*)&Y[(size_t)row * Hc + col] = make_float2(a0, a1);
}

// Transposed-store GEMM for predictor operands. Grid (96,8), 256 threads.
//   bx < 32:  AuT[256][512]  = (xA_users  @ Wup + bvu)^T
//   bx >= 32: ApT[256][1024] = (xA_papers @ Wpp + bvp)^T
__global__ void k_gemm_t(const float* __restrict__ xA, const float* __restrict__ Wup,
                         const float* __restrict__ Wpp, const float* __restrict__ bvu,
                         const float* __restrict__ bvp, float* __restrict__ AuT,
                         float* __restrict__ ApT) {
    int t = threadIdx.x, tx = t & 15, ty = t >> 4;
    int bx = blockIdx.x;
    int col = blockIdx.y * 32 + tx * 2;
    const float* X; const float* W; const float* bias; float* YT; int ldy; int rloc;
    if (bx < 32) { X = xA;                   W = Wup; bias = bvu; YT = AuT; ldy = Uc; rloc = bx * 16 + ty; }
    else         { X = xA + (size_t)Uc * Hc; W = Wpp; bias = bvp; YT = ApT; ldy = Pc; rloc = (bx - 32) * 16 + ty; }
    float a0 = 0.f, a1 = 0.f;
    gemm_core16<Hc>(X + (size_t)rloc * Hc, W + col, Hc, a0, a1);
    YT[(size_t)col * ldy + rloc]       = a0 + bias[col];
    YT[(size_t)(col + 1) * ldy + rloc] = a1 + bias[col + 1];
}

// ---------------- GCN gather: out[i,f] = relu(di * (hs[i,f] + sum hs[col,f]) + b[f])
// hs is pre-scaled by dis[row] in the GEMM epilogue -> pure unweighted sum here.
// One block per node, 256 threads (one per feature).
__global__ void k_gcn_gather(const float* __restrict__ hs, const int* __restrict__ offs,
                             const int* __restrict__ col, const float* __restrict__ dis,
                             const float* __restrict__ bias, float* __restrict__ out) {
    __shared__ int sidx[256];
    int i = blockIdx.x;
    int f = threadIdx.x;
    float di = dis[i];
    float acc = hs[i * Hc + f];    // self-loop term (x di at the end)
    int e0 = offs[i], e1 = offs[i + 1];
    for (int base = e0; base < e1; base += 256) {
        int cnt = min(256, e1 - base);
        __syncthreads();
        if (f < cnt) sidx[f] = col[base + f] * Hc;
        __syncthreads();
        int j = 0;
        for (; j + 8 <= cnt; j += 8) {
            float h0 = hs[sidx[j] + f],     h1 = hs[sidx[j + 1] + f];
            float h2 = hs[sidx[j + 2] + f], h3 = hs[sidx[j + 3] + f];
            float h4 = hs[sidx[j + 4] + f], h5 = hs[sidx[j + 5] + f];
            float h6 = hs[sidx[j + 6] + f], h7 = hs[sidx[j + 7] + f];
            float s01 = h0 + h1, s23 = h2 + h3, s45 = h4 + h5, s67 = h6 + h7;
            float s0123 = s01 + s23, s4567 = s45 + s67;
            acc += s0123 + s4567;
        }
        for (; j < cnt; j++) acc += hs[sidx[j] + f];
    }
    out[i * Hc + f] = fmaxf(di * acc + bias[f], 0.f);
}

// ---------------- predictor ----------------
// pred[u,p] = sigmoid( sum_k relu(AuT[k][u] + ApT[k][p]) * Wq2[k] + bq2 )
// Grid (16,16) = 256 blocks; 256 threads; 4 users x 2 papers / thread. No LDS.
__global__ void k_pred(const float* __restrict__ AuT, const float* __restrict__ ApT,
                       const float* __restrict__ Wq2, const float* __restrict__ bq2,
                       float* __restrict__ out) {
    int t = threadIdx.x;
    int ub = blockIdx.x * 32, pb = blockIdx.y * 64;
    int tu = t >> 5, tp = t & 31;          // tu 0..7 (4 users), tp 0..31 (2 papers)
    const float* aup = AuT + ub + tu * 4;
    const float* app = ApT + pb + tp * 2;
    float acc[4][2] = {};
#pragma unroll 2
    for (int k = 0; k < Hc; k += 4) {
        float4 wv = *(const float4*)&Wq2[k];   // wave-uniform -> s_load
        float4 a[4];
        float2 p[4];
#pragma unroll
        for (int j = 0; j < 4; j++) a[j] = *(const float4*)(aup + (size_t)(k + j) * Uc);
#pragma unroll
        for (int j = 0; j < 4; j++) p[j] = *(const float2*)(app + (size_t)(k + j) * Pc);
        const float* w = (const float*)&wv;
#pragma unroll
        for (int j = 0; j < 4; j++) {
            const float* av = (const float*)&a[j];
            float p0 = p[j].x, p1 = p[j].y;
#pragma unroll
            for (int r = 0; r < 4; r++) {
                acc[r][0] += fmaxf(av[r] + p0, 0.f) * w[j];
                acc[r][1] += fmaxf(av[r] + p1, 0.f) * w[j];
            }
        }
    }
    float bq = bq2[0];
#pragma unroll
    for (int r = 0; r < 4; r++) {
        int u = ub + tu * 4 + r;
        float2 o;
        o.x = 1.f / (1.f + __expf(-(acc[r][0] + bq)));
        o.y = 1.f / (1.f + __expf(-(acc[r][1] + bq)));
        *(float2*)&out[(size_t)u * Pc + pb + tp * 2] = o;
    }
}

// ---------------- launcher ----------------

extern "C" void kernel_launch(void* const* d_in, const int* in_sizes, int n_in,
                              void* d_out, int out_size, void* d_ws, size_t ws_size,
                              hipStream_t stream) {
    const int*   uid = (const int*)d_in[0];
    const int*   pid = (const int*)d_in[1];
    const int*   ei  = (const int*)d_in[2];   // [2,E]: src = ei[0..E), dst = ei[E..2E)
    const float* ue  = (const float*)d_in[4];
    const float* pe  = (const float*)d_in[5];
    const float* W0  = (const float*)d_in[6];  const float* b0 = (const float*)d_in[7];
    const float* W1  = (const float*)d_in[8];  const float* b1 = (const float*)d_in[9];
    const float* W2  = (const float*)d_in[10]; const float* b2 = (const float*)d_in[11];
    const float* Wu  = (const float*)d_in[12]; const float* bu = (const float*)d_in[13];
    const float* Wp  = (const float*)d_in[14]; const float* bp = (const float*)d_in[15];
    const float* Wq1 = (const float*)d_in[16]; const float* bq1 = (const float*)d_in[17];
    const float* Wq2 = (const float*)d_in[18]; const float* bq2 = (const float*)d_in[19];

    const int* e_src = ei;
    const int* e_dst = ei + Ec;

    char* w = (char*)d_ws;
    auto alloc = [&](size_t bytes) { char* p = w; w += (bytes + 255) & ~size_t(255); return p; };
    int*   deg    = (int*)alloc(Nc * 4);
    int*   offs   = (int*)alloc((Nc + 1) * 4);
    int*   cursor = (int*)alloc(Nc * 4);
    int*   col    = (int*)alloc(Ec * 4);
    float* dis    = (float*)alloc(Nc * 4);
    float* xA     = (float*)alloc((size_t)Nc * Hc * 4);
    float* Hbuf   = (float*)alloc((size_t)Nc * Hc * 4);
    float* Wup    = (float*)alloc((size_t)Hc * Hc * 4);
    float* Wpp    = (float*)alloc((size_t)Hc * Hc * 4);
    float* bvu    = (float*)alloc(Hc * 4);
    float* bvp    = (float*)alloc(Hc * 4);
    float* AuT    = (float*)alloc((size_t)Hc * Uc * 4);
    float* ApT    = (float*)alloc((size_t)Hc * Pc * 4);
    float* pred   = (float*)d_out;

    // CSR by dst
    hipMemsetAsync(deg, 0, Nc * 4, stream);
    k_hist<<<Ec / 256, 256, 0, stream>>>(e_dst, deg);
    k_scan<<<1, 256, 0, stream>>>(deg, offs, cursor, dis);
    k_scatter<<<Ec / 256, 256, 0, stream>>>(e_src, e_dst, cursor, col);

    // Collapsed predictor-input weights + biases (no upstream deps)
    k_wprep<<<dim3(16, 8, 3), 256, 0, stream>>>(Wu, Wp, Wq1, bu, bp, bq1, Wup, Wpp, bvu, bvp);

    // Layer 0 (embedding gather fused into GEMM, dis-scaled epilogue)
    k_gemm_l0<<<dim3(Nc / 16, Hc / 32), 256, 0, stream>>>(uid, pid, ue, pe, W0, dis, Hbuf);
    k_gcn_gather<<<Nc, Hc, 0, stream>>>(Hbuf, offs, col, dis, b0, xA);
    // Layer 1
    k_gemm_s<Hc><<<dim3(Nc / 16, Hc / 32), 256, 0, stream>>>(xA, W1, dis, Hbuf, Hc);
    k_gcn_gather<<<Nc, Hc, 0, stream>>>(Hbuf, offs, col, dis, b1, xA);
    // Layer 2
    k_gemm_s<Hc><<<dim3(Nc / 16, Hc / 32), 256, 0, stream>>>(xA, W2, dis, Hbuf, Hc);
    k_gcn_gather<<<Nc, Hc, 0, stream>>>(Hbuf, offs, col, dis, b2, xA);

    // AuT / ApT (transposed store), merged launch
    k_gemm_t<<<dim3(96, 8), 256, 0, stream>>>(xA, Wup, Wpp, bvu, bvp, AuT, ApT);

    // predictor
    k_pred<<<dim3(Uc / 32, Pc / 64), 256, 0, stream>>>(AuT, ApT, Wq2, bq2, pred);
}